// Round 1
// 77.936 us; speedup vs baseline: 1.0646x; 1.0646x over previous
//
#include <hip/hip_runtime.h>
#include <math.h>

// Spectral NS projection step, 512x512 fp32 periodic — radix-8 register FFT.
//
// 4 kernels (v2: kB split, no redundant forward column FFTs):
//  A : partial (stencil) + fwd row FFT. 2 rows/block (2 waves); transposed
//      write of Zt via LDS pairing -> float4 (16B) scatter.
//  B1: fwd col FFT, fully coalesced: Zt[j] -> spectrum S[j].
//  B2: 2 cols/block; read S[j] + mirror S[mj] (no recompute), exact
//      1000-step-Jacobi spectral multiplier, inv col FFT, paired float4
//      transposed write of W1.
//  C : inv row FFT + out = partial - grad(phi).
//
// Multiplier (exact identity): M = r^1000 - (1-r^1000)/(4-s), r=s/4,
//   s=2cos ai+2cos aj;  4-s = 4(sin^2(ai/2)+sin^2(aj/2)) (cancellation-free)
//   W(k) = (beta/2)[(sx^2+sy^2) Z(k) + (sx+i sy)^2 conj(Z(-k))], beta=-10M/512^2
// sin/cos over k stepped by pi/8 Givens rotation (1 sincosf per thread).
//
// Stockham radix-8, 3 stages, reads always buf[t+64m] (conflict-free);
// scatter writes padded by idx+(idx>>3) -> near-uniform bank usage.

#define HH 512
#define WW 512
#define NCELL (HH * WW)
#define NU_C 0.1f
#define PI_F 3.14159265358979323846f
#define PADDED 576   // pad(511)=574

__device__ __forceinline__ int padi(int i) { return i + (i >> 3); }

__device__ __forceinline__ float2 cadd(float2 a, float2 b) { return make_float2(a.x + b.x, a.y + b.y); }
__device__ __forceinline__ float2 csub(float2 a, float2 b) { return make_float2(a.x - b.x, a.y - b.y); }
__device__ __forceinline__ float2 cmul(float2 a, float2 b) {
    return make_float2(a.x * b.x - a.y * b.y, a.x * b.y + a.y * b.x);
}

// twiddle tables are stored FORWARD (cis(-theta)); inverse conjugates on use
template <int S>
__device__ __forceinline__ float2 cmul_tw(float2 a, float2 w) {
    float wy = (S < 0) ? w.y : -w.y;
    return make_float2(a.x * w.x - a.y * wy, a.x * wy + a.y * w.x);
}

// 8-point DFT, S=-1 forward (e^{-2pi i km/8}), S=+1 inverse
template <int S>
__device__ __forceinline__ void bfly8(float2 r[8]) {
    const float c = 0.70710678118654752f;
    const float s = (float)S;
    float2 e0 = cadd(r[0], r[4]), f0 = csub(r[0], r[4]);
    float2 e1 = cadd(r[2], r[6]), f1 = csub(r[2], r[6]);
    float2 g0 = cadd(r[1], r[5]), h0 = csub(r[1], r[5]);
    float2 g1 = cadd(r[3], r[7]), h1 = csub(r[3], r[7]);
    float2 E0 = cadd(e0, e1), E2 = csub(e0, e1);
    float2 if1 = make_float2(-s * f1.y, s * f1.x);       // s*i*f1
    float2 E1 = cadd(f0, if1), E3 = csub(f0, if1);
    float2 O0 = cadd(g0, g1), O2 = csub(g0, g1);
    float2 ih1 = make_float2(-s * h1.y, s * h1.x);
    float2 O1 = cadd(h0, ih1), O3 = csub(h0, ih1);
    float2 t1 = make_float2(c * (O1.x - s * O1.y), c * (O1.y + s * O1.x)); // W8^s1 * O1
    float2 t2 = make_float2(-s * O2.y, s * O2.x);                          // s*i*O2
    float2 t3 = make_float2(-c * (O3.x + s * O3.y), -c * (O3.y - s * O3.x));
    r[0] = cadd(E0, O0); r[4] = csub(E0, O0);
    r[1] = cadd(E1, t1); r[5] = csub(E1, t1);
    r[2] = cadd(E2, t2); r[6] = csub(E2, t2);
    r[3] = cadd(E3, t3); r[7] = csub(E3, t3);
}

struct Twid { float2 s1[8]; float2 s2[8]; };

__device__ __forceinline__ void make_tw(Twid& tw, int t) {
    float sn, cs;
    sincosf(-2.0f * PI_F * (float)(t & 7) * (1.0f / 64.0f), &sn, &cs);
    float2 T1 = make_float2(cs, sn);
    tw.s1[0] = make_float2(1.0f, 0.0f);
#pragma unroll
    for (int m = 1; m < 8; ++m) tw.s1[m] = cmul(tw.s1[m - 1], T1);
    sincosf(-2.0f * PI_F * (float)t * (1.0f / 512.0f), &sn, &cs);
    float2 T2 = make_float2(cs, sn);
    tw.s2[0] = make_float2(1.0f, 0.0f);
#pragma unroll
    for (int m = 1; m < 8; ++m) tw.s2[m] = cmul(tw.s2[m - 1], T2);
}

// 512-pt Stockham radix-8, one wave. In: r[m] = x[t+64m]. Out: r[k] = X[t+64k].
template <int S>
__device__ __forceinline__ void fft512(float2 r[8], const Twid& tw,
                                       float2* b0, float2* b1, int t) {
    bfly8<S>(r);
#pragma unroll
    for (int k = 0; k < 8; ++k) b0[padi(8 * t + k)] = r[k];
    __syncthreads();
#pragma unroll
    for (int m = 0; m < 8; ++m) r[m] = b0[padi(t + 64 * m)];
#pragma unroll
    for (int m = 1; m < 8; ++m) r[m] = cmul_tw<S>(r[m], tw.s1[m]);
    bfly8<S>(r);
    int base = ((t >> 3) << 6) + (t & 7);
#pragma unroll
    for (int k = 0; k < 8; ++k) b1[padi(base + 8 * k)] = r[k];
    __syncthreads();
#pragma unroll
    for (int m = 0; m < 8; ++m) r[m] = b1[padi(t + 64 * m)];
#pragma unroll
    for (int m = 1; m < 8; ++m) r[m] = cmul_tw<S>(r[m], tw.s2[m]);
    bfly8<S>(r);
}

// --------------------------------------------- phase A: stencil + row FFT
// 2 rows per block (wave w -> row 2b+w); paired float4 transposed store.
__global__ __launch_bounds__(128) void kA(const float* __restrict__ X,
                                          const float* __restrict__ F,
                                          float* __restrict__ p,
                                          float2* __restrict__ Zt) {
    __shared__ float2 b0[2][PADDED], b1[2][PADDED];
    int b = blockIdx.x;
    int w = threadIdx.x >> 6, t = threadIdx.x & 63;
    int i = 2 * b + w;
    Twid tw; make_tw(tw, t);
    int ip = (i + 1) & 511, im = (i + 511) & 511;
    const float* X0 = X;
    const float* X1 = X + NCELL;
    float2 r[8];
#pragma unroll
    for (int m = 0; m < 8; ++m) {
        int j = t + 64 * m;
        int jp = (j + 1) & 511, jm = (j + 511) & 511;
        float x0c = X0[i * WW + j], x1c = X1[i * WW + j];
        float aip = X0[ip * WW + j], aim = X0[im * WW + j];
        float ajp = X0[i * WW + jp], ajm = X0[i * WW + jm];
        float p0 = -(x0c * (aip - aim) * 0.5f + x1c * (ajp - ajm) * 0.5f)
                 + NU_C * (aip + aim + ajp + ajm - 4.0f * x0c) + F[i * WW + j];
        float bip = X1[ip * WW + j], bim = X1[im * WW + j];
        float bjp = X1[i * WW + jp], bjm = X1[i * WW + jm];
        float p1 = -(x0c * (bip - bim) * 0.5f + x1c * (bjp - bjm) * 0.5f)
                 + NU_C * (bip + bim + bjp + bjm - 4.0f * x1c) + F[NCELL + i * WW + j];
        p[i * WW + j] = p0;
        p[NCELL + i * WW + j] = p1;
        r[m] = make_float2(p0, p1);
    }
    fft512<-1>(r, tw, b0[w], b1[w], t);
    // stage spectrum in LDS (natural order), then write Zt[f][2b..2b+1] as float4
#pragma unroll
    for (int k = 0; k < 8; ++k) b0[w][t + 64 * k] = r[k];
    __syncthreads();
#pragma unroll
    for (int q = 0; q < 4; ++q) {
        int f = threadIdx.x + 128 * q;
        float2 v0 = b0[0][f], v1 = b0[1][f];
        *reinterpret_cast<float4*>(&Zt[f * 512 + 2 * b]) = make_float4(v0.x, v0.y, v1.x, v1.y);
    }
}

// --------------------------- phase B1: forward col FFT (fully coalesced)
__global__ __launch_bounds__(64) void kB1(const float2* __restrict__ Zt,
                                          float2* __restrict__ S) {
    __shared__ float2 b0[PADDED], b1[PADDED];
    int j = blockIdx.x, t = threadIdx.x;
    Twid tw; make_tw(tw, t);
    float2 r[8];
#pragma unroll
    for (int m = 0; m < 8; ++m) r[m] = Zt[j * 512 + t + 64 * m];
    fft512<-1>(r, tw, b0, b1, t);
#pragma unroll
    for (int k = 0; k < 8; ++k) S[j * 512 + t + 64 * k] = r[k];
}

// ------- phase B2: spectral multiplier + inverse col FFT (2 cols/block)
__global__ __launch_bounds__(128) void kB2(const float2* __restrict__ S,
                                           float2* __restrict__ W1) {
    __shared__ float2 b0[2][PADDED], b1[2][PADDED];
    int b = blockIdx.x;
    int w = threadIdx.x >> 6, t = threadIdx.x & 63;
    int j = 2 * b + w;
    int mj = (512 - j) & 511;
    Twid tw; make_tw(tw, t);

    float shy, chy;
    sincosf(PI_F * (float)j * (1.0f / 512.0f), &shy, &chy);
    float sy = 2.0f * shy * chy;   // sin(2 pi j/512)
    float qy = shy * shy;          // sin^2(pi j/512)

    // sin/cos(pi*ki/512) stepped by pi/8 per k (exact-constant Givens rotation)
    float sh, ch;
    sincosf(PI_F * (float)t * (1.0f / 512.0f), &sh, &ch);
    const float c8 = 0.92387953251128675613f;  // cos(pi/8)
    const float s8 = 0.38268343236508977173f;  // sin(pi/8)

    float2 r[8];
#pragma unroll
    for (int k = 0; k < 8; ++k) {
        int ki = t + 64 * k;
        int mi = (HH - ki) & 511;
        float2 z  = S[j * 512 + ki];           // Z(k), coalesced
        float2 zc = S[mj * 512 + mi];          // Z(-k), reverse-coalesced
        float sx = 2.0f * sh * ch;
        float qx = sh * sh;
        float qs = qx + qy;        // (4-s)/4 in [0,2]; 0 only at k=0
        float beta = 0.0f;
        if (ki != 0 || j != 0) {
            float rN;              // r^1000 = |r|^1000, r = 1-qs
            if (qs < 1.0f)      rN = expf(1000.0f * log1pf(-qs));
            else if (qs > 1.0f) rN = expf(1000.0f * logf(qs - 1.0f));
            else                rN = 0.0f;
            float M = rN - (1.0f - rN) / (4.0f * qs);
            beta = -10.0f * M * (1.0f / (512.0f * 512.0f));
        }
        float su  = sx * sx + sy * sy;
        float u2x = sx * sx - sy * sy;
        float u2y = 2.0f * sx * sy;
        float cx = zc.x, cy = -zc.y;           // conj(Z(-k))
        float tx = u2x * cx - u2y * cy;
        float ty = u2x * cy + u2y * cx;
        float bh = 0.5f * beta;
        r[k] = make_float2(bh * (su * z.x + tx), bh * (su * z.y + ty));
        float nch = ch * c8 - sh * s8;         // advance angle by pi/8
        sh = sh * c8 + ch * s8;
        ch = nch;
    }

    fft512<1>(r, tw, b0[w], b1[w], t);
    // stage in LDS (natural order), then write W1[ki][2b..2b+1] as float4
#pragma unroll
    for (int k = 0; k < 8; ++k) b0[w][t + 64 * k] = r[k];
    __syncthreads();
#pragma unroll
    for (int q = 0; q < 4; ++q) {
        int f = threadIdx.x + 128 * q;
        float2 v0 = b0[0][f], v1 = b0[1][f];
        *reinterpret_cast<float4*>(&W1[f * 512 + 2 * b]) = make_float4(v0.x, v0.y, v1.x, v1.y);
    }
}

// --------------------------------------- phase C: inverse row FFT + output
__global__ __launch_bounds__(64) void kC(const float2* __restrict__ W1,
                                         const float* __restrict__ p,
                                         float* __restrict__ out) {
    __shared__ float2 b0[PADDED], b1[PADDED];
    int i = blockIdx.x, t = threadIdx.x;
    Twid tw; make_tw(tw, t);
    float2 r[8];
#pragma unroll
    for (int m = 0; m < 8; ++m) r[m] = W1[i * 512 + t + 64 * m];
    fft512<1>(r, tw, b0, b1, t);
#pragma unroll
    for (int k = 0; k < 8; ++k) {
        int j = t + 64 * k;
        float2 w = r[k];
        out[i * WW + j]         = p[i * WW + j]         - w.x;
        out[NCELL + i * WW + j] = p[NCELL + i * WW + j] - w.y;
    }
}

// ---------------------------------------------------------------------------
extern "C" void kernel_launch(void* const* d_in, const int* in_sizes, int n_in,
                              void* d_out, int out_size, void* d_ws, size_t ws_size,
                              hipStream_t stream) {
    const float* X = (const float*)d_in[1];
    const float* F = (const float*)d_in[2];
    float* out = (float*)d_out;
    float* ws  = (float*)d_ws;

    float*  p  = ws;                          // 2*NCELL floats (2 MB)
    float2* Zt = (float2*)(ws + 2 * NCELL);   // NCELL float2 (2 MB)
    float2* S  = Zt + NCELL;                  // NCELL float2 (2 MB)
    float2* W1 = S + NCELL;                   // NCELL float2 (2 MB)

    kA <<<dim3(256), dim3(128), 0, stream>>>(X, F, p, Zt);
    kB1<<<dim3(512), dim3(64),  0, stream>>>(Zt, S);
    kB2<<<dim3(256), dim3(128), 0, stream>>>(S, W1);
    kC <<<dim3(512), dim3(64),  0, stream>>>(W1, p, out);
}